// Round 14
// baseline (384.549 us; speedup 1.0000x reference)
//
#include <hip/hip_runtime.h>
#include <hip/hip_bf16.h>
#include <hip/hip_fp16.h>

#define LRELU(v) ((v) >= 0.f ? (v) : 0.2f * (v))

typedef unsigned int uint;

static const int EPB = 4096;   // edges per bucketing block
static const int BWN = 64;     // nodes per bucket (dst >> 6)
static const int NXB = 256;    // xstats role blocks
static const int NEB = 1024;   // estats role blocks
static const int NRB = 512;    // readout blocks

__device__ inline __half2 shfl_xor_h2(__half2 v, int m) {
    int i = *(int*)&v;
    i = __shfl_xor(i, m);
    return *(__half2*)&i;
}

// ---------------- pass1: fused xstats + estats + bucket histogram ----------------
__global__ __launch_bounds__(256) void pass1(const float4* __restrict__ x4, int n4,
                                             const float4* __restrict__ e4, int E,
                                             const int* __restrict__ ei_dst,
                                             float* __restrict__ xstats,
                                             float* __restrict__ estats,
                                             uint* __restrict__ cnt, int NB) {
    __shared__ float ls[32];
    __shared__ uint hist[1024];
    int t = threadIdx.x, b = blockIdx.x;
    if (b < NXB) {                       // ---- x stats ----
        if (t < 32) ls[t] = 0.f;
        __syncthreads();
        float s1[4] = {0,0,0,0}, s2[4] = {0,0,0,0};
        int j4 = (t & 3) * 4;            // stride % 4 == 0
        for (int i = b * 256 + t; i < n4; i += NXB * 256) {
            float4 v = x4[i];
            s1[0] += v.x; s2[0] += v.x * v.x;
            s1[1] += v.y; s2[1] += v.y * v.y;
            s1[2] += v.z; s2[2] += v.z * v.z;
            s1[3] += v.w; s2[3] += v.w * v.w;
        }
        #pragma unroll
        for (int k = 0; k < 4; ++k) {
            atomicAdd(&ls[j4 + k], s1[k]);
            atomicAdd(&ls[16 + j4 + k], s2[k]);
        }
        __syncthreads();
        if (t < 32) atomicAdd(&xstats[t], ls[t]);
    } else if (b < NXB + NEB) {          // ---- eattr stats ----
        if (t < 8) ls[t] = 0.f;
        __syncthreads();
        float s1[4] = {0,0,0,0}, s2[4] = {0,0,0,0};
        for (int e = (b - NXB) * 256 + t; e < E; e += NEB * 256) {
            float4 v = e4[e];
            s1[0] += v.x; s2[0] += v.x * v.x;
            s1[1] += v.y; s2[1] += v.y * v.y;
            s1[2] += v.z; s2[2] += v.z * v.z;
            s1[3] += v.w; s2[3] += v.w * v.w;
        }
        #pragma unroll
        for (int k = 0; k < 4; ++k) {
            atomicAdd(&ls[k], s1[k]);
            atomicAdd(&ls[4 + k], s2[k]);
        }
        __syncthreads();
        if (t < 8) atomicAdd(&estats[t], ls[t]);
    } else {                             // ---- bucket histogram ----
        int hb = b - NXB - NEB;
        for (int i = t; i < NB; i += 256) hist[i] = 0;
        __syncthreads();
        int e0 = hb * EPB, e1 = min(e0 + EPB, E);
        for (int e = e0 + t; e < e1; e += 256)
            atomicAdd(&hist[ei_dst[e] >> 6], 1u);
        __syncthreads();
        for (int i = t; i < NB; i += 256) cnt[(size_t)hb * NB + i] = hist[i];
    }
}

// normalize x and store as fp16 (rows of 16)
__global__ __launch_bounds__(256) void xnorm_kernel(const float4* __restrict__ x4,
                                                    __half2* __restrict__ xn2,
                                                    const float* __restrict__ xstats,
                                                    int n4, float invN) {
    int stride = gridDim.x * blockDim.x;
    for (int i = blockIdx.x * blockDim.x + threadIdx.x; i < n4; i += stride) {
        int j4 = (i & 3) * 4;
        float4 v = x4[i];
        float o[4], in[4] = {v.x, v.y, v.z, v.w};
        #pragma unroll
        for (int k = 0; k < 4; ++k) {
            float mu = xstats[j4 + k] * invN;
            float var = xstats[16 + j4 + k] * invN - mu * mu;
            o[k] = (in[k] - mu) * rsqrtf(var + 1e-5f);
        }
        xn2[2 * i]     = __floats2half2_rn(o[0], o[1]);
        xn2[2 * i + 1] = __floats2half2_rn(o[2], o[3]);
    }
}

// ---------------- scan cnt columns in place; total[k] ----------------
__global__ __launch_bounds__(256) void scanB(uint* __restrict__ cnt,
                                             uint* __restrict__ total, int NBLK, int NB) {
    int k = blockIdx.x;
    int t = threadIdx.x, lane = t & 63, w = t >> 6;
    __shared__ uint wsum[4], woff[4], ctot;
    uint carry = 0;
    int chunks = (NBLK + 255) >> 8;
    for (int c = 0; c < chunks; ++c) {
        int b = (c << 8) + t;
        uint v = (b < NBLK) ? cnt[(size_t)b * NB + k] : 0u;
        uint inc = v;
        #pragma unroll
        for (int d = 1; d < 64; d <<= 1) {
            uint u = __shfl_up(inc, d);
            if (lane >= d) inc += u;
        }
        if (lane == 63) wsum[w] = inc;
        __syncthreads();
        if (t == 0) {
            uint s = 0;
            #pragma unroll
            for (int i = 0; i < 4; ++i) { woff[i] = s; s += wsum[i]; }
            ctot = s;
        }
        __syncthreads();
        if (b < NBLK) cnt[(size_t)b * NB + k] = carry + woff[w] + inc - v;
        carry += ctot;
        __syncthreads();
    }
    if (t == 0) total[k] = carry;
}

// ---------------- scan totals -> base; + per-graph inverse counts ----------------
__global__ __launch_bounds__(256) void scanB2(const uint* __restrict__ total,
                                              uint* __restrict__ base, int NB,
                                              const int* __restrict__ batch, int N,
                                              float* __restrict__ invcnt) {
    int t = threadIdx.x, lane = t & 63, w = t >> 6;
    __shared__ uint wsum[4], woff[4], ctot;
    uint carry = 0;
    int chunks = (NB + 255) >> 8;
    for (int c = 0; c < chunks; ++c) {
        int k = (c << 8) + t;
        uint v = (k < NB) ? total[k] : 0u;
        uint inc = v;
        #pragma unroll
        for (int d = 1; d < 64; d <<= 1) {
            uint u = __shfl_up(inc, d);
            if (lane >= d) inc += u;
        }
        if (lane == 63) wsum[w] = inc;
        __syncthreads();
        if (t == 0) {
            uint s = 0;
            #pragma unroll
            for (int i = 0; i < 4; ++i) { woff[i] = s; s += wsum[i]; }
            ctot = s;
        }
        __syncthreads();
        if (k < NB) base[k] = carry + woff[w] + inc - v;
        carry += ctot;
        __syncthreads();
    }
    if (t == 0) base[NB] = carry;
    if (t < 64) {                       // per-graph counts via binary search
        int g = t;
        int lo = 0, hi = N;
        while (lo < hi) { int m = (lo + hi) >> 1; if (batch[m] < g) lo = m + 1; else hi = m; }
        int start = lo;
        hi = N;
        while (lo < hi) { int m = (lo + hi) >> 1; if (batch[m] < g + 1) lo = m + 1; else hi = m; }
        invcnt[g] = 1.f / fmaxf((float)(lo - start), 1.f);
    }
}

// ---------------- bucket-grouped scatter: ONE fused 16B record per edge ----------------
// rec = {src | dl<<16, ea01(h2), ea23(h2), 0}
__global__ __launch_bounds__(256) void scatterC(const int* __restrict__ ei,
                                                const float4* __restrict__ eattr,
                                                const uint* __restrict__ cnt,
                                                const uint* __restrict__ base,
                                                const float* __restrict__ estats,
                                                uint4* __restrict__ rec,
                                                int E, int NB, float invE) {
    __shared__ uint cur[1024];
    int t = threadIdx.x, b = blockIdx.x;
    for (int i = t; i < NB; i += 256)
        cur[i] = base[i] + cnt[(size_t)b * NB + i];
    float mu[4], rs[4];
    #pragma unroll
    for (int j = 0; j < 4; ++j) {
        mu[j] = estats[j] * invE;
        float var = estats[4 + j] * invE - mu[j] * mu[j];
        rs[j] = rsqrtf(var + 1e-5f);
    }
    __syncthreads();
    int e0 = b * EPB, e1 = min(e0 + EPB, E);
    for (int e = e0 + t; e < e1; e += 256) {
        int src = ei[e];
        int dst = ei[E + e];
        float4 v = eattr[e];
        uint pos = atomicAdd(&cur[dst >> 6], 1u);
        uint4 q;
        q.x = (uint)src | ((uint)(dst & 63) << 16);
        *(__half2*)&q.y = __floats2half2_rn((v.x - mu[0]) * rs[0], (v.y - mu[1]) * rs[1]);
        *(__half2*)&q.z = __floats2half2_rn((v.z - mu[2]) * rs[2], (v.w - mu[3]) * rs[3]);
        q.w = 0u;
        rec[pos] = q;
    }
}

// ---------------- in-bucket counting sort -> CSR + offs + fused EA segment sum ----------------
__global__ __launch_bounds__(256) void sort2(const uint4* __restrict__ rec,
                                             const uint* __restrict__ base,
                                             uint* __restrict__ src_sorted,
                                             uint2* __restrict__ ea_sorted,
                                             int* __restrict__ offs,
                                             float4* __restrict__ EA, int N, int E) {
    __shared__ uint hist[64], excl[64], cur[64];
    int t = threadIdx.x, k = blockIdx.x;
    if (t < 64) hist[t] = 0;
    __syncthreads();
    int e0 = base[k], e1 = base[k + 1];
    for (int e = e0 + t; e < e1; e += 256)
        atomicAdd(&hist[(rec[e].x >> 16) & 63], 1u);
    __syncthreads();
    if (t < 64) {
        uint v = hist[t];
        uint inc = v;
        #pragma unroll
        for (int d = 1; d < 64; d <<= 1) {
            uint u = __shfl_up(inc, d);
            if (t >= d) inc += u;
        }
        excl[t] = inc - v;
        cur[t] = inc - v;
        int node = k * 64 + t;
        if (node < N) offs[node] = (int)(e0 + inc - v);
    }
    if (t == 0 && k == 0) offs[N] = E;
    __syncthreads();
    for (int e = e0 + t; e < e1; e += 256) {
        uint4 r = rec[e];
        int dl = (r.x >> 16) & 63;
        uint pos = e0 + atomicAdd(&cur[dl], 1u);
        src_sorted[pos] = r.x & 0xffffu;
        ea_sorted[pos] = make_uint2(r.y, r.z);
    }
    __syncthreads();
    // fused EA: 4 lanes per node
    int dl = t >> 2, q = t & 3;
    int node = k * 64 + dl;
    int s0 = e0 + (int)excl[dl], s1 = e0 + (int)cur[dl];
    float4 acc = make_float4(0.f, 0.f, 0.f, 0.f);
    for (int e = s0 + q; e < s1; e += 4) {
        uint2 v = ea_sorted[e];
        float2 a = __half22float2(*(__half2*)&v.x);
        float2 c = __half22float2(*(__half2*)&v.y);
        acc.x += a.x; acc.y += a.y; acc.z += c.x; acc.w += c.y;
    }
    #pragma unroll
    for (int d = 1; d < 4; d <<= 1) {
        acc.x += __shfl_xor(acc.x, d);
        acc.y += __shfl_xor(acc.y, d);
        acc.z += __shfl_xor(acc.z, d);
        acc.w += __shfl_xor(acc.w, d);
    }
    if (q == 0 && node < N) EA[node] = acc;
}

// ---------------- fused conv layer ----------------
// 16 nodes/block. Gather: wave w handles its 4 nodes SEQUENTIALLY (unroll 1 -> low VGPR),
// 8 groups of 8 lanes; FULL 8-WAY EDGE UNROLL per 64-edge batch: all 8 src loads issue
// independently, then all 8 row loads (each depends only on its own src) -> ~1 round trip
// per batch instead of 8. Dual accumulator banks halve the hadd2 serial chain.
// Epilogue: block-wide, 240 threads = 5 f-groups x 48 features; weights amortized 3-4x.
template <int FIN>
__global__ __launch_bounds__(256, 4) void conv_kernel(const __half* __restrict__ hin,
                                                      const float4* __restrict__ EA,
                                                      const int* __restrict__ offs,
                                                      const uint* __restrict__ src_sorted,
                                                      const float* __restrict__ Wr,
                                                      const float* __restrict__ Wm,
                                                      const float* __restrict__ b,
                                                      __half* __restrict__ hout, int N) {
    __shared__ float gbuf[16][FIN];
    __shared__ float hbuf[16][FIN];
    int t = threadIdx.x, w = t >> 6, lane = t & 63;
    int g = lane >> 3, j = lane & 7;
    int nb = blockIdx.x * 16;

    #pragma unroll 1
    for (int i = 0; i < 4; ++i) {
        int node = nb + w * 4 + i;
        if (node < N) {
            int s0 = offs[node], s1 = offs[node + 1];
            int row = w * 4 + i;
            if (FIN == 16) {
                __half2 accA = __floats2half2_rn(0.f, 0.f), accB = accA;
                for (int base = s0; base < s1; base += 64) {
                    #pragma unroll
                    for (int k = 0; k < 8; ++k) {
                        int e = base + g + 8 * k;
                        if (e < s1) {
                            int s = (int)src_sorted[e];
                            __half2 v = ((const __half2*)(hin + (size_t)s * 16))[j];
                            if (k & 1) accB = __hadd2(accB, v);
                            else       accA = __hadd2(accA, v);
                        }
                    }
                }
                accA = __hadd2(accA, accB);
                #pragma unroll
                for (int m = 8; m < 64; m <<= 1) accA = __hadd2(accA, shfl_xor_h2(accA, m));
                if (g == 0) {
                    float2 f = __half22float2(accA);
                    gbuf[row][2 * j] = f.x; gbuf[row][2 * j + 1] = f.y;
                }
                if (lane < 16) hbuf[row][lane] = __half2float(hin[(size_t)node * 16 + lane]);
            } else {
                __half2 a0 = __floats2half2_rn(0.f, 0.f), a1 = a0, a2 = a0, a3 = a0;
                __half2 a4 = a0, a5 = a0, a6 = a0, a7 = a0;
                for (int base = s0; base < s1; base += 64) {
                    #pragma unroll
                    for (int k = 0; k < 8; ++k) {
                        int e = base + g + 8 * k;
                        if (e < s1) {
                            int s = (int)src_sorted[e];
                            if (j < 6) {
                                uint4 q = *(const uint4*)(hin + (size_t)s * 48 + 8 * j);
                                if (k & 1) {
                                    a4 = __hadd2(a4, *(__half2*)&q.x);
                                    a5 = __hadd2(a5, *(__half2*)&q.y);
                                    a6 = __hadd2(a6, *(__half2*)&q.z);
                                    a7 = __hadd2(a7, *(__half2*)&q.w);
                                } else {
                                    a0 = __hadd2(a0, *(__half2*)&q.x);
                                    a1 = __hadd2(a1, *(__half2*)&q.y);
                                    a2 = __hadd2(a2, *(__half2*)&q.z);
                                    a3 = __hadd2(a3, *(__half2*)&q.w);
                                }
                            }
                        }
                    }
                }
                a0 = __hadd2(a0, a4); a1 = __hadd2(a1, a5);
                a2 = __hadd2(a2, a6); a3 = __hadd2(a3, a7);
                #pragma unroll
                for (int m = 8; m < 64; m <<= 1) {
                    a0 = __hadd2(a0, shfl_xor_h2(a0, m));
                    a1 = __hadd2(a1, shfl_xor_h2(a1, m));
                    a2 = __hadd2(a2, shfl_xor_h2(a2, m));
                    a3 = __hadd2(a3, shfl_xor_h2(a3, m));
                }
                if (g == 0 && j < 6) {
                    float2 f0 = __half22float2(a0), f1 = __half22float2(a1);
                    float2 f2 = __half22float2(a2), f3 = __half22float2(a3);
                    int f = 8 * j;
                    gbuf[row][f + 0] = f0.x; gbuf[row][f + 1] = f0.y;
                    gbuf[row][f + 2] = f1.x; gbuf[row][f + 3] = f1.y;
                    gbuf[row][f + 4] = f2.x; gbuf[row][f + 5] = f2.y;
                    gbuf[row][f + 6] = f3.x; gbuf[row][f + 7] = f3.y;
                }
                if (lane < 48) hbuf[row][lane] = __half2float(hin[(size_t)node * 48 + lane]);
            }
        }
    }
    __syncthreads();

    if (t < 240) {
        int gg = t / 48, f = t - gg * 48;           // 5 groups x 48 features
        int i0 = gg, i1 = gg + 5, i2 = gg + 10;     // owned rows; gg==0 also owns 15
        float acc0 = 0.f, acc1 = 0.f, acc2 = 0.f, acc3 = 0.f;
        #pragma unroll 4
        for (int k = 0; k < FIN; ++k) {
            float wr = Wr[k * 48 + f];
            float wm = Wm[k * 48 + f];
            acc0 += hbuf[i0][k] * wr + gbuf[i0][k] * wm;
            acc1 += hbuf[i1][k] * wr + gbuf[i1][k] * wm;
            acc2 += hbuf[i2][k] * wr + gbuf[i2][k] * wm;
            if (gg == 0) acc3 += hbuf[15][k] * wr + gbuf[15][k] * wm;
        }
        float bb = b[f];
        float wmE0 = Wm[(FIN + 0) * 48 + f];
        float wmE1 = Wm[(FIN + 1) * 48 + f];
        float wmE2 = Wm[(FIN + 2) * 48 + f];
        float wmE3 = Wm[(FIN + 3) * 48 + f];
        int rows[4] = {i0, i1, i2, 15};
        float accs[4] = {acc0, acc1, acc2, acc3};
        int nown = (gg == 0) ? 4 : 3;
        for (int q = 0; q < nown; ++q) {
            int node = nb + rows[q];
            if (node < N) {
                float4 ea = EA[node];
                float a = accs[q] + bb + ea.x * wmE0 + ea.y * wmE1 + ea.z * wmE2 + ea.w * wmE3;
                hout[(size_t)node * 48 + f] = __float2half(LRELU(a));
            }
        }
    }
}

// ---------------- high-occupancy atomic readout (h rows of 48) ----------------
__global__ __launch_bounds__(256) void readout_atomic(const __half* __restrict__ h,
                                                      const int* __restrict__ batch,
                                                      const float* __restrict__ invcnt,
                                                      float* __restrict__ hcat,
                                                      int N, int c, int l) {
    int t = threadIdx.x;
    int lane = t & 63;
    int j = t & 7;
    int gid = (blockIdx.x * 256 + t) >> 3;   // global 8-lane group id
    int n0 = gid * c, n1 = min(n0 + c, N);
    float2 a0 = {0.f, 0.f}, a1 = {0.f, 0.f}, a2 = {0.f, 0.f};
    int cg = -1;
    for (int n = n0; n < n1; ++n) {
        int g = batch[n];
        if (g != cg) {
            if (cg >= 0) {
                float s = invcnt[cg];
                float* dst = hcat + cg * 144 + l * 48;
                atomicAdd(dst + 2 * j, a0.x * s);      atomicAdd(dst + 2 * j + 1, a0.y * s);
                atomicAdd(dst + 16 + 2 * j, a1.x * s); atomicAdd(dst + 17 + 2 * j, a1.y * s);
                atomicAdd(dst + 32 + 2 * j, a2.x * s); atomicAdd(dst + 33 + 2 * j, a2.y * s);
            }
            cg = g;
            a0 = make_float2(0.f, 0.f); a1 = a0; a2 = a0;
        }
        const __half2* hp = (const __half2*)(h + (size_t)n * 48);
        float2 v0 = __half22float2(hp[j]);
        float2 v1 = __half22float2(hp[8 + j]);
        float2 v2 = __half22float2(hp[16 + j]);
        a0.x += v0.x; a0.y += v0.y;
        a1.x += v1.x; a1.y += v1.y;
        a2.x += v2.x; a2.y += v2.y;
    }
    // wave-level combine when all 8 groups in this wave ended on the same graph
    int lead = __shfl(cg, 0);
    bool uni = __all(cg == lead) && lead >= 0;
    if (uni) {
        #pragma unroll
        for (int m = 8; m < 64; m <<= 1) {
            a0.x += __shfl_xor(a0.x, m); a0.y += __shfl_xor(a0.y, m);
            a1.x += __shfl_xor(a1.x, m); a1.y += __shfl_xor(a1.y, m);
            a2.x += __shfl_xor(a2.x, m); a2.y += __shfl_xor(a2.y, m);
        }
        if (lane < 8) {
            float s = invcnt[lead];
            float* dst = hcat + lead * 144 + l * 48;
            atomicAdd(dst + 2 * j, a0.x * s);      atomicAdd(dst + 2 * j + 1, a0.y * s);
            atomicAdd(dst + 16 + 2 * j, a1.x * s); atomicAdd(dst + 17 + 2 * j, a1.y * s);
            atomicAdd(dst + 32 + 2 * j, a2.x * s); atomicAdd(dst + 33 + 2 * j, a2.y * s);
        }
    } else if (cg >= 0) {
        float s = invcnt[cg];
        float* dst = hcat + cg * 144 + l * 48;
        atomicAdd(dst + 2 * j, a0.x * s);      atomicAdd(dst + 2 * j + 1, a0.y * s);
        atomicAdd(dst + 16 + 2 * j, a1.x * s); atomicAdd(dst + 17 + 2 * j, a1.y * s);
        atomicAdd(dst + 32 + 2 * j, a2.x * s); atomicAdd(dst + 33 + 2 * j, a2.y * s);
    }
}

// ---------------- final MLP: one block per graph (hcat already means) ----------------
__global__ __launch_bounds__(128) void mlp_kernel(const float* __restrict__ hcat,
                                                  const float* __restrict__ Wl1, const float* __restrict__ bl1,
                                                  const float* __restrict__ Wl2, const float* __restrict__ bl2,
                                                  const float* __restrict__ Wf, const float* __restrict__ bf,
                                                  float* __restrict__ out) {
    int g = blockIdx.x, t = threadIdx.x;
    __shared__ float buf[144];
    __shared__ float l1[128];
    for (int i = t; i < 144; i += 128) buf[i] = hcat[g * 144 + i];
    __syncthreads();
    float acc = bl1[t];
    for (int k = 0; k < 144; ++k) acc += buf[k] * Wl1[k * 128 + t];
    acc = LRELU(acc);
    l1[t] = acc;
    __syncthreads();
    float acc2 = bl2[t];
    for (int k = 0; k < 128; ++k) acc2 += l1[k] * Wl2[k * 128 + t];
    acc2 = LRELU(acc2);
    __syncthreads();
    buf[t] = acc2;
    __syncthreads();
    if (t < 4) {
        float a = bf[t];
        for (int k = 0; k < 128; ++k) a += buf[k] * Wf[k * 4 + t];
        out[g * 4 + t] = a;
    }
}

extern "C" void kernel_launch(void* const* d_in, const int* in_sizes, int n_in,
                              void* d_out, int out_size, void* d_ws, size_t ws_size,
                              hipStream_t stream) {
    const float* x     = (const float*)d_in[0];
    const float* eattr = (const float*)d_in[1];
    const float* Wr0 = (const float*)d_in[2];
    const float* Wm0 = (const float*)d_in[3];
    const float* b0  = (const float*)d_in[4];
    const float* Wr1 = (const float*)d_in[5];
    const float* Wm1 = (const float*)d_in[6];
    const float* b1  = (const float*)d_in[7];
    const float* Wr2 = (const float*)d_in[8];
    const float* Wm2 = (const float*)d_in[9];
    const float* b2  = (const float*)d_in[10];
    const float* Wl1 = (const float*)d_in[11];
    const float* bl1 = (const float*)d_in[12];
    const float* Wl2 = (const float*)d_in[13];
    const float* bl2 = (const float*)d_in[14];
    const float* Wf  = (const float*)d_in[15];
    const float* bf  = (const float*)d_in[16];
    const int* ei    = (const int*)d_in[17];
    const int* batch = (const int*)d_in[18];

    int N = in_sizes[0] / 16;
    int E = in_sizes[1] / 4;
    int NB = (N + BWN - 1) / BWN;
    int NBLK = (E + EPB - 1) / EPB;

    // ---- workspace layout (16B-aligned first) ----
    char* p = (char*)d_ws;
    float4* EA       = (float4*)p;                p += (size_t)N * 16;
    uint4* rec       = (uint4*)p;                 p += (size_t)E * 16;
    uint2* ea_sorted = (uint2*)p;                 p += (size_t)E * 8;
    __half* xn   = (__half*)p;                    p += (size_t)N * 16 * 2;
    __half* h16a = (__half*)p;                    p += (size_t)N * 48 * 2;
    __half* h16b = (__half*)p;                    p += (size_t)N * 48 * 2;
    uint* src_sorted = (uint*)p;                  p += (size_t)E * 4;
    uint* cnt        = (uint*)p;                  p += (size_t)NBLK * NB * 4;
    uint* total      = (uint*)p;                  p += (size_t)NB * 4;
    uint* base       = (uint*)p;                  p += (size_t)(NB + 1) * 4;
    int*  offs       = (int*)p;                   p += (size_t)(N + 1) * 4;
    float* estats    = (float*)p;                 p += 8 * 4;
    float* xstats    = (float*)p;                 p += 32 * 4;
    float* hcat      = (float*)p;                 p += 64 * 144 * 4;
    float* invcnt    = (float*)p;                 p += 64 * 4;

    // zero: estats + xstats + hcat + invcnt (contiguous)
    hipMemsetAsync(estats, 0, (8 + 32 + 64 * 144 + 64) * sizeof(float), stream);

    int n4 = N * 4;
    pass1<<<NXB + NEB + NBLK, 256, 0, stream>>>((const float4*)x, n4, (const float4*)eattr, E,
                                                ei + E, xstats, estats, cnt, NB);
    xnorm_kernel<<<256, 256, 0, stream>>>((const float4*)x, (__half2*)xn, xstats, n4, 1.f / N);
    scanB<<<NB, 256, 0, stream>>>(cnt, total, NBLK, NB);
    scanB2<<<1, 256, 0, stream>>>(total, base, NB, batch, N, invcnt);
    scatterC<<<NBLK, 256, 0, stream>>>(ei, (const float4*)eattr, cnt, base, estats,
                                       rec, E, NB, 1.f / E);
    sort2<<<NB, 256, 0, stream>>>(rec, base, src_sorted, ea_sorted, offs, EA, N, E);

    int c = (N + NRB * 32 - 1) / (NRB * 32);   // nodes per 8-lane group
    conv_kernel<16><<<(N + 15) / 16, 256, 0, stream>>>(xn, EA, offs, src_sorted, Wr0, Wm0, b0, h16a, N);
    readout_atomic<<<NRB, 256, 0, stream>>>(h16a, batch, invcnt, hcat, N, c, 0);
    conv_kernel<48><<<(N + 15) / 16, 256, 0, stream>>>(h16a, EA, offs, src_sorted, Wr1, Wm1, b1, h16b, N);
    readout_atomic<<<NRB, 256, 0, stream>>>(h16b, batch, invcnt, hcat, N, c, 1);
    conv_kernel<48><<<(N + 15) / 16, 256, 0, stream>>>(h16b, EA, offs, src_sorted, Wr2, Wm2, b2, h16a, N);
    readout_atomic<<<NRB, 256, 0, stream>>>(h16a, batch, invcnt, hcat, N, c, 2);

    mlp_kernel<<<64, 128, 0, stream>>>(hcat, Wl1, bl1, Wl2, bl2, Wf, bf, (float*)d_out);
}

// Round 15
// 329.258 us; speedup vs baseline: 1.1679x; 1.1679x over previous
//
#include <hip/hip_runtime.h>
#include <hip/hip_bf16.h>
#include <hip/hip_fp16.h>

#define LRELU(v) ((v) >= 0.f ? (v) : 0.2f * (v))

typedef unsigned int uint;
typedef _Float16 h2v __attribute__((ext_vector_type(2)));

static const int EPB = 4096;   // edges per bucketing block
static const int BWN = 64;     // nodes per bucket (dst >> 6)
static const int NXB = 256;    // xstats role blocks
static const int NEB = 1024;   // estats role blocks

__device__ inline __half2 shfl_xor_h2(__half2 v, int m) {
    int i = *(int*)&v;
    i = __shfl_xor(i, m);
    return *(__half2*)&i;
}

__device__ inline float fdot2(__half2 a, __half2 b, float c) {
#if __has_builtin(__builtin_amdgcn_fdot2)
    return __builtin_amdgcn_fdot2(*(h2v*)&a, *(h2v*)&b, c, false);
#else
    float2 fa = __half22float2(a), fb = __half22float2(b);
    return c + fa.x * fb.x + fa.y * fb.y;
#endif
}

// ---------------- pass1: fused xstats + estats + bucket histogram ----------------
__global__ __launch_bounds__(256) void pass1(const float4* __restrict__ x4, int n4,
                                             const float4* __restrict__ e4, int E,
                                             const int* __restrict__ ei_dst,
                                             float* __restrict__ xstats,
                                             float* __restrict__ estats,
                                             uint* __restrict__ cnt, int NB) {
    __shared__ float ls[32];
    __shared__ uint hist[1024];
    int t = threadIdx.x, b = blockIdx.x;
    if (b < NXB) {                       // ---- x stats ----
        if (t < 32) ls[t] = 0.f;
        __syncthreads();
        float s1[4] = {0,0,0,0}, s2[4] = {0,0,0,0};
        int j4 = (t & 3) * 4;
        for (int i = b * 256 + t; i < n4; i += NXB * 256) {
            float4 v = x4[i];
            s1[0] += v.x; s2[0] += v.x * v.x;
            s1[1] += v.y; s2[1] += v.y * v.y;
            s1[2] += v.z; s2[2] += v.z * v.z;
            s1[3] += v.w; s2[3] += v.w * v.w;
        }
        #pragma unroll
        for (int k = 0; k < 4; ++k) {
            atomicAdd(&ls[j4 + k], s1[k]);
            atomicAdd(&ls[16 + j4 + k], s2[k]);
        }
        __syncthreads();
        if (t < 32) atomicAdd(&xstats[t], ls[t]);
    } else if (b < NXB + NEB) {          // ---- eattr stats ----
        if (t < 8) ls[t] = 0.f;
        __syncthreads();
        float s1[4] = {0,0,0,0}, s2[4] = {0,0,0,0};
        for (int e = (b - NXB) * 256 + t; e < E; e += NEB * 256) {
            float4 v = e4[e];
            s1[0] += v.x; s2[0] += v.x * v.x;
            s1[1] += v.y; s2[1] += v.y * v.y;
            s1[2] += v.z; s2[2] += v.z * v.z;
            s1[3] += v.w; s2[3] += v.w * v.w;
        }
        #pragma unroll
        for (int k = 0; k < 4; ++k) {
            atomicAdd(&ls[k], s1[k]);
            atomicAdd(&ls[4 + k], s2[k]);
        }
        __syncthreads();
        if (t < 8) atomicAdd(&estats[t], ls[t]);
    } else {                             // ---- bucket histogram ----
        int hb = b - NXB - NEB;
        for (int i = t; i < NB; i += 256) hist[i] = 0;
        __syncthreads();
        int e0 = hb * EPB, e1 = min(e0 + EPB, E);
        for (int e = e0 + t; e < e1; e += 256)
            atomicAdd(&hist[ei_dst[e] >> 6], 1u);
        __syncthreads();
        for (int i = t; i < NB; i += 256) cnt[(size_t)hb * NB + i] = hist[i];
    }
}

// normalize x and store as fp16 (rows of 16)
__global__ __launch_bounds__(256) void xnorm_kernel(const float4* __restrict__ x4,
                                                    __half2* __restrict__ xn2,
                                                    const float* __restrict__ xstats,
                                                    int n4, float invN) {
    int stride = gridDim.x * blockDim.x;
    for (int i = blockIdx.x * blockDim.x + threadIdx.x; i < n4; i += stride) {
        int j4 = (i & 3) * 4;
        float4 v = x4[i];
        float o[4], in[4] = {v.x, v.y, v.z, v.w};
        #pragma unroll
        for (int k = 0; k < 4; ++k) {
            float mu = xstats[j4 + k] * invN;
            float var = xstats[16 + j4 + k] * invN - mu * mu;
            o[k] = (in[k] - mu) * rsqrtf(var + 1e-5f);
        }
        xn2[2 * i]     = __floats2half2_rn(o[0], o[1]);
        xn2[2 * i + 1] = __floats2half2_rn(o[2], o[3]);
    }
}

// ---------------- weight prep: transpose + fp16 pack: wT[f][kk] kk<FIN:Wr, FIN..2FIN+3:Wm ----------------
__global__ __launch_bounds__(256) void wprep(const float* __restrict__ Wr0, const float* __restrict__ Wm0,
                                             const float* __restrict__ Wr1, const float* __restrict__ Wm1,
                                             const float* __restrict__ Wr2, const float* __restrict__ Wm2,
                                             __half* __restrict__ wT16, __half* __restrict__ wT48a,
                                             __half* __restrict__ wT48b) {
    int b = blockIdx.x, t = threadIdx.x;
    int FIN = (b == 0) ? 16 : 48;
    int WP  = (b == 0) ? 40 : 112;
    const float* Wr = (b == 0) ? Wr0 : (b == 1 ? Wr1 : Wr2);
    const float* Wm = (b == 0) ? Wm0 : (b == 1 ? Wm1 : Wm2);
    __half* out = (b == 0) ? wT16 : (b == 1 ? wT48a : wT48b);
    int tot = 48 * (2 * FIN + 4);
    for (int idx = t; idx < tot; idx += 256) {
        int f = idx / (2 * FIN + 4), kk = idx - f * (2 * FIN + 4);
        float v = (kk < FIN) ? Wr[kk * 48 + f] : Wm[(kk - FIN) * 48 + f];
        out[(size_t)f * WP + kk] = __float2half(v);
    }
}

// ---------------- scan cnt columns in place; total[k] ----------------
__global__ __launch_bounds__(256) void scanB(uint* __restrict__ cnt,
                                             uint* __restrict__ total, int NBLK, int NB) {
    int k = blockIdx.x;
    int t = threadIdx.x, lane = t & 63, w = t >> 6;
    __shared__ uint wsum[4], woff[4], ctot;
    uint carry = 0;
    int chunks = (NBLK + 255) >> 8;
    for (int c = 0; c < chunks; ++c) {
        int b = (c << 8) + t;
        uint v = (b < NBLK) ? cnt[(size_t)b * NB + k] : 0u;
        uint inc = v;
        #pragma unroll
        for (int d = 1; d < 64; d <<= 1) {
            uint u = __shfl_up(inc, d);
            if (lane >= d) inc += u;
        }
        if (lane == 63) wsum[w] = inc;
        __syncthreads();
        if (t == 0) {
            uint s = 0;
            #pragma unroll
            for (int i = 0; i < 4; ++i) { woff[i] = s; s += wsum[i]; }
            ctot = s;
        }
        __syncthreads();
        if (b < NBLK) cnt[(size_t)b * NB + k] = carry + woff[w] + inc - v;
        carry += ctot;
        __syncthreads();
    }
    if (t == 0) total[k] = carry;
}

// ---------------- scan totals -> base; + per-graph inverse counts ----------------
__global__ __launch_bounds__(256) void scanB2(const uint* __restrict__ total,
                                              uint* __restrict__ base, int NB,
                                              const int* __restrict__ batch, int N,
                                              float* __restrict__ invcnt) {
    int t = threadIdx.x, lane = t & 63, w = t >> 6;
    __shared__ uint wsum[4], woff[4], ctot;
    uint carry = 0;
    int chunks = (NB + 255) >> 8;
    for (int c = 0; c < chunks; ++c) {
        int k = (c << 8) + t;
        uint v = (k < NB) ? total[k] : 0u;
        uint inc = v;
        #pragma unroll
        for (int d = 1; d < 64; d <<= 1) {
            uint u = __shfl_up(inc, d);
            if (lane >= d) inc += u;
        }
        if (lane == 63) wsum[w] = inc;
        __syncthreads();
        if (t == 0) {
            uint s = 0;
            #pragma unroll
            for (int i = 0; i < 4; ++i) { woff[i] = s; s += wsum[i]; }
            ctot = s;
        }
        __syncthreads();
        if (k < NB) base[k] = carry + woff[w] + inc - v;
        carry += ctot;
        __syncthreads();
    }
    if (t == 0) base[NB] = carry;
    if (t < 64) {
        int g = t;
        int lo = 0, hi = N;
        while (lo < hi) { int m = (lo + hi) >> 1; if (batch[m] < g) lo = m + 1; else hi = m; }
        int start = lo;
        hi = N;
        while (lo < hi) { int m = (lo + hi) >> 1; if (batch[m] < g + 1) lo = m + 1; else hi = m; }
        invcnt[g] = 1.f / fmaxf((float)(lo - start), 1.f);
    }
}

// ---------------- bucket-grouped scatter: ONE fused 16B record per edge ----------------
__global__ __launch_bounds__(256) void scatterC(const int* __restrict__ ei,
                                                const float4* __restrict__ eattr,
                                                const uint* __restrict__ cnt,
                                                const uint* __restrict__ base,
                                                const float* __restrict__ estats,
                                                uint4* __restrict__ rec,
                                                int E, int NB, float invE) {
    __shared__ uint cur[1024];
    int t = threadIdx.x, b = blockIdx.x;
    for (int i = t; i < NB; i += 256)
        cur[i] = base[i] + cnt[(size_t)b * NB + i];
    float mu[4], rs[4];
    #pragma unroll
    for (int j = 0; j < 4; ++j) {
        mu[j] = estats[j] * invE;
        float var = estats[4 + j] * invE - mu[j] * mu[j];
        rs[j] = rsqrtf(var + 1e-5f);
    }
    __syncthreads();
    int e0 = b * EPB, e1 = min(e0 + EPB, E);
    for (int e = e0 + t; e < e1; e += 256) {
        int src = ei[e];
        int dst = ei[E + e];
        float4 v = eattr[e];
        uint pos = atomicAdd(&cur[dst >> 6], 1u);
        uint4 q;
        q.x = (uint)src | ((uint)(dst & 63) << 16);
        *(__half2*)&q.y = __floats2half2_rn((v.x - mu[0]) * rs[0], (v.y - mu[1]) * rs[1]);
        *(__half2*)&q.z = __floats2half2_rn((v.z - mu[2]) * rs[2], (v.w - mu[3]) * rs[3]);
        q.w = 0u;
        rec[pos] = q;
    }
}

// ---------------- in-bucket counting sort -> CSR + offs + fused EA segment sum ----------------
__global__ __launch_bounds__(256) void sort2(const uint4* __restrict__ rec,
                                             const uint* __restrict__ base,
                                             uint* __restrict__ src_sorted,
                                             uint2* __restrict__ ea_sorted,
                                             int* __restrict__ offs,
                                             float4* __restrict__ EA, int N, int E) {
    __shared__ uint hist[64], excl[64], cur[64];
    int t = threadIdx.x, k = blockIdx.x;
    if (t < 64) hist[t] = 0;
    __syncthreads();
    int e0 = base[k], e1 = base[k + 1];
    for (int e = e0 + t; e < e1; e += 256)
        atomicAdd(&hist[(rec[e].x >> 16) & 63], 1u);
    __syncthreads();
    if (t < 64) {
        uint v = hist[t];
        uint inc = v;
        #pragma unroll
        for (int d = 1; d < 64; d <<= 1) {
            uint u = __shfl_up(inc, d);
            if (t >= d) inc += u;
        }
        excl[t] = inc - v;
        cur[t] = inc - v;
        int node = k * 64 + t;
        if (node < N) offs[node] = (int)(e0 + inc - v);
    }
    if (t == 0 && k == 0) offs[N] = E;
    __syncthreads();
    for (int e = e0 + t; e < e1; e += 256) {
        uint4 r = rec[e];
        int dl = (r.x >> 16) & 63;
        uint pos = e0 + atomicAdd(&cur[dl], 1u);
        src_sorted[pos] = r.x & 0xffffu;
        ea_sorted[pos] = make_uint2(r.y, r.z);
    }
    __syncthreads();
    int dl = t >> 2, q = t & 3;
    int node = k * 64 + dl;
    int s0 = e0 + (int)excl[dl], s1 = e0 + (int)cur[dl];
    float4 acc = make_float4(0.f, 0.f, 0.f, 0.f);
    for (int e = s0 + q; e < s1; e += 4) {
        uint2 v = ea_sorted[e];
        float2 a = __half22float2(*(__half2*)&v.x);
        float2 c = __half22float2(*(__half2*)&v.y);
        acc.x += a.x; acc.y += a.y; acc.z += c.x; acc.w += c.y;
    }
    #pragma unroll
    for (int d = 1; d < 4; d <<= 1) {
        acc.x += __shfl_xor(acc.x, d);
        acc.y += __shfl_xor(acc.y, d);
        acc.z += __shfl_xor(acc.z, d);
        acc.w += __shfl_xor(acc.w, d);
    }
    if (q == 0 && node < N) EA[node] = acc;
}

// ---------------- fused conv layer + readout ----------------
// 16 nodes/block. Gather (2-way unroll, fp16 LDS). Epilogue: fp16 packed dot (fdot2) with
// pre-transposed fp16 weights from global L1; fused per-graph readout (<=2 graphs/block).
template <int FIN>
__global__ __launch_bounds__(256) void conv_kernel(const __half* __restrict__ hin,
                                                   const float4* __restrict__ EA,
                                                   const int* __restrict__ offs,
                                                   const uint* __restrict__ src_sorted,
                                                   const __half* __restrict__ wT,
                                                   const float* __restrict__ b,
                                                   const int* __restrict__ batch,
                                                   const float* __restrict__ invcnt,
                                                   float* __restrict__ hcat, int l,
                                                   __half* __restrict__ hout, int N) {
    constexpr int HP = (FIN == 48) ? 28 : 12;   // row stride in __half2 (16B-aligned, bank-spread)
    constexpr int WP = (FIN == 48) ? 112 : 40;  // wT row stride in halves
    __shared__ __half2 gbuf2[16][HP];
    __shared__ __half2 hbuf2[16][HP];
    __shared__ float rsum[5][2][48];
    __shared__ int bid[16];
    int t = threadIdx.x, w = t >> 6, lane = t & 63;
    int g = lane >> 3, j = lane & 7;
    int nb = blockIdx.x * 16;
    if (t < 16) bid[t] = (nb + t < N) ? batch[nb + t] : -1;

    #pragma unroll 1
    for (int i = 0; i < 4; ++i) {
        int node = nb + w * 4 + i;
        if (node < N) {
            int s0 = offs[node], s1 = offs[node + 1];
            int row = w * 4 + i;
            if (FIN == 16) {
                __half2 accA = __floats2half2_rn(0.f, 0.f), accB = accA;
                int e = s0 + g;
                for (; e + 8 < s1; e += 16) {
                    int sA = (int)src_sorted[e];
                    int sB = (int)src_sorted[e + 8];
                    accA = __hadd2(accA, ((const __half2*)(hin + (size_t)sA * 16))[j]);
                    accB = __hadd2(accB, ((const __half2*)(hin + (size_t)sB * 16))[j]);
                }
                if (e < s1) {
                    int sA = (int)src_sorted[e];
                    accA = __hadd2(accA, ((const __half2*)(hin + (size_t)sA * 16))[j]);
                }
                accA = __hadd2(accA, accB);
                #pragma unroll
                for (int m = 8; m < 64; m <<= 1) accA = __hadd2(accA, shfl_xor_h2(accA, m));
                if (g == 0) gbuf2[row][j] = accA;
                if (lane < 8) hbuf2[row][lane] = ((const __half2*)(hin + (size_t)node * 16))[lane];
            } else {
                __half2 a0 = __floats2half2_rn(0.f, 0.f), a1 = a0, a2 = a0, a3 = a0;
                __half2 a4 = a0, a5 = a0, a6 = a0, a7 = a0;
                int e = s0 + g;
                for (; e + 8 < s1; e += 16) {
                    int sA = (int)src_sorted[e];
                    int sB = (int)src_sorted[e + 8];
                    if (j < 6) {
                        uint4 qa = *(const uint4*)(hin + (size_t)sA * 48 + 8 * j);
                        uint4 qb = *(const uint4*)(hin + (size_t)sB * 48 + 8 * j);
                        a0 = __hadd2(a0, *(__half2*)&qa.x);
                        a1 = __hadd2(a1, *(__half2*)&qa.y);
                        a2 = __hadd2(a2, *(__half2*)&qa.z);
                        a3 = __hadd2(a3, *(__half2*)&qa.w);
                        a4 = __hadd2(a4, *(__half2*)&qb.x);
                        a5 = __hadd2(a5, *(__half2*)&qb.y);
                        a6 = __hadd2(a6, *(__half2*)&qb.z);
                        a7 = __hadd2(a7, *(__half2*)&qb.w);
                    }
                }
                if (e < s1) {
                    int sA = (int)src_sorted[e];
                    if (j < 6) {
                        uint4 qa = *(const uint4*)(hin + (size_t)sA * 48 + 8 * j);
                        a0 = __hadd2(a0, *(__half2*)&qa.x);
                        a1 = __hadd2(a1, *(__half2*)&qa.y);
                        a2 = __hadd2(a2, *(__half2*)&qa.z);
                        a3 = __hadd2(a3, *(__half2*)&qa.w);
                    }
                }
                a0 = __hadd2(a0, a4); a1 = __hadd2(a1, a5);
                a2 = __hadd2(a2, a6); a3 = __hadd2(a3, a7);
                #pragma unroll
                for (int m = 8; m < 64; m <<= 1) {
                    a0 = __hadd2(a0, shfl_xor_h2(a0, m));
                    a1 = __hadd2(a1, shfl_xor_h2(a1, m));
                    a2 = __hadd2(a2, shfl_xor_h2(a2, m));
                    a3 = __hadd2(a3, shfl_xor_h2(a3, m));
                }
                if (g == 0 && j < 6) {
                    gbuf2[row][4 * j + 0] = a0;
                    gbuf2[row][4 * j + 1] = a1;
                    gbuf2[row][4 * j + 2] = a2;
                    gbuf2[row][4 * j + 3] = a3;
                }
                if (lane < 24) hbuf2[row][lane] = ((const __half2*)(hin + (size_t)node * 48))[lane];
            }
        }
    }
    __syncthreads();

    if (t < 240) {
        int gg = t / 48, f = t - gg * 48;
        int rows[4] = {gg, gg + 5, gg + 10, 15};
        int nown = (gg == 0) ? 4 : 3;
        const __half* wf = wT + (size_t)f * WP;
        float acc[4] = {0.f, 0.f, 0.f, 0.f};
        #pragma unroll
        for (int kb = 0; kb < FIN / 8; ++kb) {
            uint4 wr8 = *(const uint4*)(wf + kb * 8);
            uint4 wm8 = *(const uint4*)(wf + FIN + kb * 8);
            #pragma unroll
            for (int q = 0; q < 4; ++q) {
                if (q < nown) {
                    uint4 h8 = *(const uint4*)&hbuf2[rows[q]][kb * 4];
                    uint4 g8 = *(const uint4*)&gbuf2[rows[q]][kb * 4];
                    #pragma unroll
                    for (int i = 0; i < 4; ++i) {
                        acc[q] = fdot2(((__half2*)&h8)[i], ((__half2*)&wr8)[i], acc[q]);
                        acc[q] = fdot2(((__half2*)&g8)[i], ((__half2*)&wm8)[i], acc[q]);
                    }
                }
            }
        }
        float wmE[4];
        {
            uint2 we = *(const uint2*)(wf + 2 * FIN);
            float2 e01 = __half22float2(((__half2*)&we)[0]);
            float2 e23 = __half22float2(((__half2*)&we)[1]);
            wmE[0] = e01.x; wmE[1] = e01.y; wmE[2] = e23.x; wmE[3] = e23.y;
        }
        float bb = b[f];
        int gFirst = bid[0];
        int gLast = bid[min(15, N - 1 - nb)];
        bool spill = (gLast > gFirst + 1);
        float rA = 0.f, rB = 0.f;
        for (int q = 0; q < nown; ++q) {
            int node = nb + rows[q];
            if (node < N) {
                float4 ea = EA[node];
                float a = acc[q] + bb + ea.x * wmE[0] + ea.y * wmE[1] + ea.z * wmE[2] + ea.w * wmE[3];
                a = LRELU(a);
                hout[(size_t)node * 48 + f] = __float2half(a);
                int gb = bid[rows[q]];
                float contrib = a * invcnt[gb];
                if (spill) atomicAdd(&hcat[gb * 144 + l * 48 + f], contrib);
                else if (gb == gFirst) rA += contrib;
                else rB += contrib;
            }
        }
        if (!spill) { rsum[gg][0][f] = rA; rsum[gg][1][f] = rB; }
    }
    __syncthreads();
    if (t < 96) {
        int slot = t / 48, f = t - slot * 48;
        int gFirst = bid[0];
        int gLast = bid[min(15, N - 1 - nb)];
        bool spill = (gLast > gFirst + 1);
        if (!spill && (slot == 0 || gLast == gFirst + 1)) {
            float s = rsum[0][slot][f] + rsum[1][slot][f] + rsum[2][slot][f]
                    + rsum[3][slot][f] + rsum[4][slot][f];
            atomicAdd(&hcat[(gFirst + slot) * 144 + l * 48 + f], s);
        }
    }
}

// ---------------- final MLP: one block per graph (hcat already means) ----------------
__global__ __launch_bounds__(128) void mlp_kernel(const float* __restrict__ hcat,
                                                  const float* __restrict__ Wl1, const float* __restrict__ bl1,
                                                  const float* __restrict__ Wl2, const float* __restrict__ bl2,
                                                  const float* __restrict__ Wf, const float* __restrict__ bf,
                                                  float* __restrict__ out) {
    int g = blockIdx.x, t = threadIdx.x;
    __shared__ float buf[144];
    __shared__ float l1[128];
    for (int i = t; i < 144; i += 128) buf[i] = hcat[g * 144 + i];
    __syncthreads();
    float acc = bl1[t];
    for (int k = 0; k < 144; ++k) acc += buf[k] * Wl1[k * 128 + t];
    acc = LRELU(acc);
    l1[t] = acc;
    __syncthreads();
    float acc2 = bl2[t];
    for (int k = 0; k < 128; ++k) acc2 += l1[k] * Wl2[k * 128 + t];
    acc2 = LRELU(acc2);
    __syncthreads();
    buf[t] = acc2;
    __syncthreads();
    if (t < 4) {
        float a = bf[t];
        for (int k = 0; k < 128; ++k) a += buf[k] * Wf[k * 4 + t];
        out[g * 4 + t] = a;
    }
}

extern "C" void kernel_launch(void* const* d_in, const int* in_sizes, int n_in,
                              void* d_out, int out_size, void* d_ws, size_t ws_size,
                              hipStream_t stream) {
    const float* x     = (const float*)d_in[0];
    const float* eattr = (const float*)d_in[1];
    const float* Wr0 = (const float*)d_in[2];
    const float* Wm0 = (const float*)d_in[3];
    const float* b0  = (const float*)d_in[4];
    const float* Wr1 = (const float*)d_in[5];
    const float* Wm1 = (const float*)d_in[6];
    const float* b1  = (const float*)d_in[7];
    const float* Wr2 = (const float*)d_in[8];
    const float* Wm2 = (const float*)d_in[9];
    const float* b2  = (const float*)d_in[10];
    const float* Wl1 = (const float*)d_in[11];
    const float* bl1 = (const float*)d_in[12];
    const float* Wl2 = (const float*)d_in[13];
    const float* bl2 = (const float*)d_in[14];
    const float* Wf  = (const float*)d_in[15];
    const float* bf  = (const float*)d_in[16];
    const int* ei    = (const int*)d_in[17];
    const int* batch = (const int*)d_in[18];

    int N = in_sizes[0] / 16;
    int E = in_sizes[1] / 4;
    int NB = (N + BWN - 1) / BWN;
    int NBLK = (E + EPB - 1) / EPB;

    // ---- workspace layout (16B-aligned first) ----
    char* p = (char*)d_ws;
    float4* EA       = (float4*)p;                p += (size_t)N * 16;
    uint4* rec       = (uint4*)p;                 p += (size_t)E * 16;
    uint2* ea_sorted = (uint2*)p;                 p += (size_t)E * 8;
    __half* xn   = (__half*)p;                    p += (size_t)N * 16 * 2;
    __half* h16a = (__half*)p;                    p += (size_t)N * 48 * 2;
    __half* h16b = (__half*)p;                    p += (size_t)N * 48 * 2;
    __half* wT16  = (__half*)p;                   p += (size_t)48 * 40 * 2;
    __half* wT48a = (__half*)p;                   p += (size_t)48 * 112 * 2;
    __half* wT48b = (__half*)p;                   p += (size_t)48 * 112 * 2;
    uint* src_sorted = (uint*)p;                  p += (size_t)E * 4;
    uint* cnt        = (uint*)p;                  p += (size_t)NBLK * NB * 4;
    uint* total      = (uint*)p;                  p += (size_t)NB * 4;
    uint* base       = (uint*)p;                  p += (size_t)(NB + 1) * 4;
    int*  offs       = (int*)p;                   p += (size_t)(N + 1) * 4;
    float* estats    = (float*)p;                 p += 8 * 4;
    float* xstats    = (float*)p;                 p += 32 * 4;
    float* hcat      = (float*)p;                 p += 64 * 144 * 4;
    float* invcnt    = (float*)p;                 p += 64 * 4;

    // zero: estats + xstats + hcat + invcnt (contiguous)
    hipMemsetAsync(estats, 0, (8 + 32 + 64 * 144 + 64) * sizeof(float), stream);

    int n4 = N * 4;
    pass1<<<NXB + NEB + NBLK, 256, 0, stream>>>((const float4*)x, n4, (const float4*)eattr, E,
                                                ei + E, xstats, estats, cnt, NB);
    xnorm_kernel<<<256, 256, 0, stream>>>((const float4*)x, (__half2*)xn, xstats, n4, 1.f / N);
    wprep<<<3, 256, 0, stream>>>(Wr0, Wm0, Wr1, Wm1, Wr2, Wm2, wT16, wT48a, wT48b);
    scanB<<<NB, 256, 0, stream>>>(cnt, total, NBLK, NB);
    scanB2<<<1, 256, 0, stream>>>(total, base, NB, batch, N, invcnt);
    scatterC<<<NBLK, 256, 0, stream>>>(ei, (const float4*)eattr, cnt, base, estats,
                                       rec, E, NB, 1.f / E);
    sort2<<<NB, 256, 0, stream>>>(rec, base, src_sorted, ea_sorted, offs, EA, N, E);

    conv_kernel<16><<<(N + 15) / 16, 256, 0, stream>>>(xn, EA, offs, src_sorted, wT16, b0,
                                                       batch, invcnt, hcat, 0, h16a, N);
    conv_kernel<48><<<(N + 15) / 16, 256, 0, stream>>>(h16a, EA, offs, src_sorted, wT48a, b1,
                                                       batch, invcnt, hcat, 1, h16b, N);
    conv_kernel<48><<<(N + 15) / 16, 256, 0, stream>>>(h16b, EA, offs, src_sorted, wT48b, b2,
                                                       batch, invcnt, hcat, 2, h16a, N);

    mlp_kernel<<<64, 128, 0, stream>>>(hcat, Wl1, bl1, Wl2, bl2, Wf, bf, (float*)d_out);
}